// Round 5
// baseline (512.821 us; speedup 1.0000x reference)
//
#include <hip/hip_runtime.h>
#include <math.h>

#define CTC_BLANK 1
#define RBW 132  // row-buffer stride (floats): 128 classes + zero slot at [128]

struct Pv { double pb, p1, p3, p5, p7; };

__device__ __forceinline__ int imax2(int a, int b) { return a > b ? a : b; }

// wave64 max of non-negative int via DPP (rocPRIM pattern); result broadcast via readlane
__device__ __forceinline__ int wave_imax_dpp(int v) {
  int t;
  t = __builtin_amdgcn_update_dpp(0, v, 0x111, 0xF, 0xF, true); v = imax2(v, t);
  t = __builtin_amdgcn_update_dpp(0, v, 0x112, 0xF, 0xF, true); v = imax2(v, t);
  t = __builtin_amdgcn_update_dpp(0, v, 0x114, 0xF, 0xF, true); v = imax2(v, t);
  t = __builtin_amdgcn_update_dpp(0, v, 0x118, 0xF, 0xF, true); v = imax2(v, t);
  t = __builtin_amdgcn_update_dpp(0, v, 0x142, 0xF, 0xF, true); v = imax2(v, t);
  t = __builtin_amdgcn_update_dpp(0, v, 0x143, 0xF, 0xF, true); v = imax2(v, t);
  return __builtin_amdgcn_readlane(v, 63);
}

// gather emission probs for this lane's slots from staged f32 row -> f64
#define GATH(P, boff)                              \
  {                                                \
    P.pb = (double)rb[(boff) + CTC_BLANK];         \
    P.p1 = (double)rb[(boff) + i1];                \
    P.p3 = (double)rb[(boff) + i3];                \
    P.p5 = (double)rb[(boff) + i5];                \
    P.p7 = (double)rb[(boff) + i7];                \
  }

// One step (consume row t = t0+J). Buffers: row r lives in rb[RBW*(r&3)].
// gather row t+1 from (J+2)&3 (written at step t-1, already complete);
// stage row t+2 (from pre) into (J+3)&3; refill pre with row t+10.
#define CTC_STEP(J, PC, PN, HMI, HMO)                                    \
  {                                                                      \
    GATH(PN, RBW * (((J) + 2) & 3));                                     \
    double t7s = (lane == 63) ? a[7] : 0.0;                              \
    double hh = (lane == 0) ? 0.0 : HMI;                                 \
    a8 = (a8 + t7s) * PC.pb;                                             \
    a[7] = fma(sk7, a[5], a[7] + a[6]) * PC.p7;                          \
    HMO = __shfl_up(a[7], 1);                                            \
    a[6] = (a[6] + a[5]) * PC.pb;                                        \
    a[5] = fma(sk5, a[3], a[5] + a[4]) * PC.p5;                          \
    a[4] = (a[4] + a[3]) * PC.pb;                                        \
    a[3] = fma(sk3, a[1], a[3] + a[2]) * PC.p3;                          \
    a[2] = (a[2] + a[1]) * PC.pb;                                        \
    a[1] = fma(sk1, hh, a[1] + a[0]) * PC.p1;                            \
    a[0] = (a[0] + hh) * PC.pb;                                          \
    {                                                                    \
      float ex = __expf(pre[(J) & 7].x), ey = __expf(pre[(J) & 7].y);    \
      *(float2*)&rb[RBW * (((J) + 3) & 3) + 2 * lane] =                  \
          make_float2(ex, ey);                                           \
      int tl_ = t0 + (J) + 10;                                           \
      if (tl_ > Tlast) tl_ = Tlast;                                      \
      pre[(J) & 7] = *(const float2*)(lpn + (size_t)tl_ * NC + 2 * lane);\
    }                                                                    \
  }

__global__ __launch_bounds__(512) void ctc_main(
    const float* __restrict__ lp, const int* __restrict__ ilen,
    const int* __restrict__ tgt, const int* __restrict__ tlen,
    int T, int N, int C, int L,
    double* __restrict__ ws_lse,   // [N*6] per-helper-wave lse partials
    double* __restrict__ ws_ll) {  // [N]   raw log A(end) + exponent track
  const int n = blockIdx.x;
  const int tid = threadIdx.x;
  const int wid = tid >> 6;
  const int lane = tid & 63;
  const int NC = N * C;
  const int Tn = ilen[n];

  if (wid == 4) return;  // keep wave0's SIMD to itself (waves 0,4 share SIMD0)

  if (wid != 0) {
    // ---- helper waves: one t-row PER LANE; no cross-lane work until the end ----
    const int h = (wid < 4) ? (wid - 1) : (wid - 2);  // 0..5
    const int per = (T + 5) / 6;
    const int tb = h * per;
    int te = tb + per;
    if (te > Tn) te = Tn;
    const float* basen = lp + (size_t)n * C;
    double acc = 0.0;
    for (int t0b = tb; t0b < te; t0b += 64) {
      int t = t0b + lane;
      if (t < te) {
        const float4* rp = (const float4*)(basen + (size_t)t * NC);
        float sx = 0.f, sy = 0.f, sz = 0.f, sw = 0.f;
        const int c4n = C >> 2;
#pragma unroll 8
        for (int c4 = 0; c4 < c4n; ++c4) {
          float4 v = rp[c4];
          sx += __expf(v.x); sy += __expf(v.y);
          sz += __expf(v.z); sw += __expf(v.w);
        }
        acc += log((double)((sx + sy) + (sz + sw)));
      }
    }
#pragma unroll
    for (int off = 32; off; off >>= 1) acc += __shfl_xor(acc, off);
    if (lane == 0) ws_lse[n * 6 + h] = acc;
    return;
  }

  // ---- wave 0: serial alpha chain, 8 states/lane + state 512 on lane 63 ----
  __shared__ float rb[4 * RBW];  // 4 row buffers; [boff+128] is a zero slot
  __shared__ double adump[513];

  const int tlv = tlen[n];
  const int gend = 2 * tlv;
  const int* tg = tgt + (size_t)n * L;

  if (lane < 4) rb[lane * RBW + 128] = 0.f;  // zero slots (dead-state gathers)

  // per-lane static data: odd slots s=1,3,5,7 -> class index + skip flag
  int i1, i3, i5, i7;
  double sk1, sk3, sk5, sk7;
  {
    int idx[4]; double sk[4];
#pragma unroll
    for (int q = 0; q < 4; ++q) {
      int s = 2 * q + 1;
      int g = lane * 8 + s;
      int k = (g - 1) >> 1;
      int kc = (k < L) ? k : (L - 1);
      int eidx = tg[kc];
      double skv = 0.;
      if (g >= 3) {
        int kp = k - 1; if (kp > L - 1) kp = L - 1;
        int ep = tg[kp];
        skv = (eidx != ep && eidx != CTC_BLANK) ? 1. : 0.;
      }
      if (g > gend) eidx = 128;  // dead state -> gathers exact 0
      idx[q] = eidx; sk[q] = skv;
    }
    i1 = idx[0]; i3 = idx[1]; i5 = idx[2]; i7 = idx[3];
    sk1 = sk[0]; sk3 = sk[1]; sk5 = sk[2]; sk7 = sk[3];
  }

  const float* lpn = lp + (size_t)n * C;
  const int Tlast = T - 1;

  // prologue: stage rows 0,1,2 into buffers 0,1,2
#pragma unroll
  for (int r = 0; r < 3; ++r) {
    int tr = (r > Tlast) ? Tlast : r;
    float2 v = *(const float2*)(lpn + (size_t)tr * NC + 2 * lane);
    *(float2*)&rb[r * RBW + 2 * lane] = make_float2(__expf(v.x), __expf(v.y));
  }

  Pv pA, pB;
  // init alpha from row 0: states 0,1 live (lane 0 slots 0,1)
  double a[8], a8 = 0.0;
  GATH(pA, 0);
  a[0] = (lane == 0) ? pA.pb : 0.0;
  a[1] = (lane == 0) ? pA.p1 : 0.0;
#pragma unroll
  for (int s = 2; s < 8; ++s) a[s] = 0.0;
  GATH(pA, RBW);  // p for step t=1 (row 1)

  // prefetch rows 3..10 (pre[j] holds row t0+j+2 at loop entry)
  float2 pre[8];
#pragma unroll
  for (int j = 0; j < 8; ++j) {
    int tl_ = 3 + j; if (tl_ > Tlast) tl_ = Tlast;
    pre[j] = *(const float2*)(lpn + (size_t)tl_ * NC + 2 * lane);
  }

  double hA = 0.0, hB = 0.0;  // pipelined halo (prev-lane a[7] of previous step)
  long long Esum = 0;
  int t0 = 1;  // invariant: t0 == 1 (mod 4), needed for buffer-index folding

  for (; t0 + 16 <= Tn; t0 += 16) {
    CTC_STEP(0,  pA, pB, hA, hB)
    CTC_STEP(1,  pB, pA, hB, hA)
    CTC_STEP(2,  pA, pB, hA, hB)
    CTC_STEP(3,  pB, pA, hB, hA)
    CTC_STEP(4,  pA, pB, hA, hB)
    CTC_STEP(5,  pB, pA, hB, hA)
    CTC_STEP(6,  pA, pB, hA, hB)
    CTC_STEP(7,  pB, pA, hB, hA)
    CTC_STEP(8,  pA, pB, hA, hB)
    CTC_STEP(9,  pB, pA, hB, hA)
    CTC_STEP(10, pA, pB, hA, hB)
    CTC_STEP(11, pB, pA, hB, hA)
    CTC_STEP(12, pA, pB, hA, hB)
    CTC_STEP(13, pB, pA, hB, hA)
    CTC_STEP(14, pA, pB, hA, hB)
    CTC_STEP(15, pB, pA, hB, hA)
    // renorm every 16 steps: int-compare hi-words (positive doubles), DPP wave
    // max, exact pow2 rescale built in scalar regs
    int hi = __double2hiint(a[0]);
    hi = imax2(hi, __double2hiint(a[1]));
    hi = imax2(hi, __double2hiint(a[2]));
    hi = imax2(hi, __double2hiint(a[3]));
    hi = imax2(hi, __double2hiint(a[4]));
    hi = imax2(hi, __double2hiint(a[5]));
    hi = imax2(hi, __double2hiint(a[6]));
    hi = imax2(hi, __double2hiint(a[7]));
    hi = imax2(hi, __double2hiint(a8));
    int mx = wave_imax_dpp(hi);
    int E = ((mx >> 20) & 0x7ff) - 1023;
    double sc = __hiloint2double((1023 - E) << 20, 0);  // exact 2^-E
    Esum += E;
#pragma unroll
    for (int s = 0; s < 8; ++s) a[s] *= sc;
    a8 *= sc;
    hA *= sc;  // pending halo carries the same scale
  }
  // tail (< 16 steps); guards are a strict prefix so halo ping-pong stays valid
  if (t0 + 0  < Tn) CTC_STEP(0,  pA, pB, hA, hB)
  if (t0 + 1  < Tn) CTC_STEP(1,  pB, pA, hB, hA)
  if (t0 + 2  < Tn) CTC_STEP(2,  pA, pB, hA, hB)
  if (t0 + 3  < Tn) CTC_STEP(3,  pB, pA, hB, hA)
  if (t0 + 4  < Tn) CTC_STEP(4,  pA, pB, hA, hB)
  if (t0 + 5  < Tn) CTC_STEP(5,  pB, pA, hB, hA)
  if (t0 + 6  < Tn) CTC_STEP(6,  pA, pB, hA, hB)
  if (t0 + 7  < Tn) CTC_STEP(7,  pB, pA, hB, hA)
  if (t0 + 8  < Tn) CTC_STEP(8,  pA, pB, hA, hB)
  if (t0 + 9  < Tn) CTC_STEP(9,  pB, pA, hB, hA)
  if (t0 + 10 < Tn) CTC_STEP(10, pA, pB, hA, hB)
  if (t0 + 11 < Tn) CTC_STEP(11, pB, pA, hB, hA)
  if (t0 + 12 < Tn) CTC_STEP(12, pA, pB, hA, hB)
  if (t0 + 13 < Tn) CTC_STEP(13, pB, pA, hB, hA)
  if (t0 + 14 < Tn) CTC_STEP(14, pA, pB, hA, hB)

  // epilogue
#pragma unroll
  for (int s = 0; s < 8; ++s) adump[lane * 8 + s] = a[s];
  if (lane == 63) adump[512] = a8;
  if (lane == 0) {
    int end = gend;
    int i2 = (end > 0) ? (end - 1) : (2 * L);
    double Ae = adump[end] + adump[i2];
    ws_ll[n] = log(Ae) + (double)Esum * 0.69314718055994530942;
  }
}

__global__ void ctc_final(const double* __restrict__ ws_lse,
                          const double* __restrict__ ws_ll,
                          float* __restrict__ out, int N) {
  __shared__ double sred[128];
  const int i = threadIdx.x;
  double l = 0.0;
  if (i < N) {
    double denom = 0.0;
#pragma unroll
    for (int h = 0; h < 6; ++h) denom += ws_lse[i * 6 + h];
    double ll = ws_ll[i] - denom;
    double ls = -ll;
    if (!isfinite(ls) || fabs(ls) >= 1e29) ls = 0.0;
    l = ls;
  }
  sred[i] = l;
  __syncthreads();
#pragma unroll
  for (int off = 64; off > 0; off >>= 1) {
    if (i < off) sred[i] += sred[i + off];
    __syncthreads();
  }
  if (i == 0) out[0] = (float)sred[0];
}

extern "C" void kernel_launch(void* const* d_in, const int* in_sizes, int n_in,
                              void* d_out, int out_size, void* d_ws, size_t ws_size,
                              hipStream_t stream) {
  (void)n_in; (void)out_size; (void)ws_size;
  const float* lp = (const float*)d_in[0];
  const int* ilen = (const int*)d_in[1];
  const int* tgt = (const int*)d_in[2];
  const int* tlen = (const int*)d_in[3];

  const int N = in_sizes[1];            // 128
  const int L = in_sizes[2] / N;        // 256
  const int C = 128;                    // classes (fixed by problem)
  const int T = in_sizes[0] / (N * C);  // 4000

  double* ws_lse = (double*)d_ws;           // N*6 doubles
  double* ws_ll = ws_lse + (size_t)N * 6;   // N doubles

  ctc_main<<<N, 512, 0, stream>>>(lp, ilen, tgt, tlen, T, N, C, L, ws_lse, ws_ll);
  ctc_final<<<1, 128, 0, stream>>>(ws_lse, ws_ll, (float*)d_out, N);
}

// Round 6
// 409.054 us; speedup vs baseline: 1.2537x; 1.2537x over previous
//
#include <hip/hip_runtime.h>
#include <math.h>

#define CTC_BLANK 1
#define RING 64     // ring slots (rows)
#define GRS 260     // floats per ring slot: [4*lane..4*lane+3]=odd p, [256]=p_blank
#define RTW 132     // producer rowtmp stride: 128 exp'd classes + zero slot [128]

struct Pv { double pb, p1, p3, p5, p7; };

__device__ __forceinline__ int imax2(int a, int b) { return a > b ? a : b; }

// wave64 max of non-negative ints via DPP; result valid on lane 63 -> readlane
__device__ __forceinline__ int wave_imax_dpp(int v) {
  int t;
  t = __builtin_amdgcn_update_dpp(0, v, 0x111, 0xF, 0xF, true); v = imax2(v, t);
  t = __builtin_amdgcn_update_dpp(0, v, 0x112, 0xF, 0xF, true); v = imax2(v, t);
  t = __builtin_amdgcn_update_dpp(0, v, 0x114, 0xF, 0xF, true); v = imax2(v, t);
  t = __builtin_amdgcn_update_dpp(0, v, 0x118, 0xF, 0xF, true); v = imax2(v, t);
  t = __builtin_amdgcn_update_dpp(0, v, 0x142, 0xF, 0xF, true); v = imax2(v, t);
  t = __builtin_amdgcn_update_dpp(0, v, 0x143, 0xF, 0xF, true); v = imax2(v, t);
  return __builtin_amdgcn_readlane(v, 63);
}

// wave64 f32 sum via DPP; total lands on lane 63
__device__ __forceinline__ float wave_fsum_dpp(float v) {
  v += __int_as_float(__builtin_amdgcn_update_dpp(0, __float_as_int(v), 0x111, 0xF, 0xF, true));
  v += __int_as_float(__builtin_amdgcn_update_dpp(0, __float_as_int(v), 0x112, 0xF, 0xF, true));
  v += __int_as_float(__builtin_amdgcn_update_dpp(0, __float_as_int(v), 0x114, 0xF, 0xF, true));
  v += __int_as_float(__builtin_amdgcn_update_dpp(0, __float_as_int(v), 0x118, 0xF, 0xF, true));
  v += __int_as_float(__builtin_amdgcn_update_dpp(0, __float_as_int(v), 0x142, 0xF, 0xF, true));
  v += __int_as_float(__builtin_amdgcn_update_dpp(0, __float_as_int(v), 0x143, 0xF, 0xF, true));
  return v;
}

// Consumer step for row t = t0+J.
// PC = f64 probs for row t (use now); PN = filled here from raw regs (row t+1,
// read 2 steps ago); then reissue raw read for row t+3.
#define CSTEP(J, PC, PN, QV, QB, HMI, HMO)                              \
  {                                                                     \
    PN.pb = (double)(QB);                                               \
    PN.p1 = (double)(QV).x;                                             \
    PN.p3 = (double)(QV).y;                                             \
    PN.p5 = (double)(QV).z;                                             \
    PN.p7 = (double)(QV).w;                                             \
    {                                                                   \
      int rr = t0 + (J) + 3;                                            \
      if (rr > TnM1) rr = TnM1;                                         \
      int sb = (rr & (RING - 1)) * GRS;                                 \
      QV = *(const float4*)&ring[sb + 4 * lane];                        \
      QB = ring[sb + 256];                                              \
    }                                                                   \
    double t7s = (lane == 63) ? a[7] : 0.0;                             \
    double hh = (lane == 0) ? 0.0 : HMI;                                \
    a8 = (a8 + t7s) * PC.pb;                                            \
    a[7] = fma(sk7, a[5], a[7] + a[6]) * PC.p7;                         \
    HMO = __shfl_up(a[7], 1);                                           \
    a[6] = (a[6] + a[5]) * PC.pb;                                       \
    a[5] = fma(sk5, a[3], a[5] + a[4]) * PC.p5;                         \
    a[4] = (a[4] + a[3]) * PC.pb;                                       \
    a[3] = fma(sk3, a[1], a[3] + a[2]) * PC.p3;                         \
    a[2] = (a[2] + a[1]) * PC.pb;                                       \
    a[1] = fma(sk1, hh, a[1] + a[0]) * PC.p1;                           \
    a[0] = (a[0] + hh) * PC.pb;                                         \
  }

// spin until all rows <= NEED are produced (capped: min_prog >= Tn-6 proves all)
#define SPIN_PROG(NEED)                                                 \
  {                                                                     \
    int need_ = (NEED);                                                 \
    int cap_ = Tn - 6;                                                  \
    if (need_ > cap_) need_ = cap_;                                     \
    for (;;) {                                                          \
      int m0 = *(volatile int*)&prog[0];                                \
      int m1 = *(volatile int*)&prog[1];                                \
      int m2 = *(volatile int*)&prog[2];                                \
      int m3 = *(volatile int*)&prog[3];                                \
      int m4 = *(volatile int*)&prog[4];                                \
      int m5 = *(volatile int*)&prog[5];                                \
      m0 = m0 < m1 ? m0 : m1;                                           \
      m2 = m2 < m3 ? m2 : m3;                                           \
      m4 = m4 < m5 ? m4 : m5;                                           \
      m0 = m0 < m2 ? m0 : m2;                                           \
      m0 = m0 < m4 ? m0 : m4;                                           \
      if (m0 >= need_) break;                                           \
      __builtin_amdgcn_s_sleep(2);                                      \
    }                                                                   \
  }                                                                     \
  asm volatile("" ::: "memory");

__global__ __launch_bounds__(512) void ctc_main(
    const float* __restrict__ lp, const int* __restrict__ ilen,
    const int* __restrict__ tgt, const int* __restrict__ tlen,
    int T, int N, int C, int L,
    double* __restrict__ ws_lse,   // [N*6] per-producer lse partials
    double* __restrict__ ws_ll) {  // [N]   raw log A(end) + exponent track
  __shared__ float ring[RING * GRS];   // 66560 B
  __shared__ float rowtmp[6 * RTW];    // 3168 B
  __shared__ int prog[6];
  __shared__ int cons;
  __shared__ double adump[513];        // 4104 B

  const int n = blockIdx.x;
  const int tid = threadIdx.x;
  const int wid = tid >> 6;
  const int lane = tid & 63;
  const int NC = N * C;
  const int Tn = ilen[n];

  if (tid < 6) prog[tid] = -1;
  if (tid == 6) cons = -1;
  __syncthreads();

  if (wid == 4) return;  // keep wave0's SIMD to itself (waves 0,4 share SIMD0)

  const int tlv = tlen[n];
  const int gend = 2 * tlv;
  const int* tg = tgt + (size_t)n * L;

  // per-lane static tables (used by producers: i*, by consumer: sk*)
  int i1, i3, i5, i7;
  double sk1, sk3, sk5, sk7;
  {
    int idx[4]; double sk[4];
#pragma unroll
    for (int q = 0; q < 4; ++q) {
      int s = 2 * q + 1;
      int g = lane * 8 + s;
      int k = (g - 1) >> 1;
      int kc = (k < L) ? k : (L - 1);
      int eidx = tg[kc];
      double skv = 0.;
      if (g >= 3) {
        int kp = k - 1; if (kp > L - 1) kp = L - 1;
        int ep = tg[kp];
        skv = (eidx != ep && eidx != CTC_BLANK) ? 1. : 0.;
      }
      if (g > gend) eidx = 128;  // dead odd state -> gathers exact 0
      idx[q] = eidx; sk[q] = skv;
    }
    i1 = idx[0]; i3 = idx[1]; i5 = idx[2]; i7 = idx[3];
    sk1 = sk[0]; sk3 = sk[1]; sk5 = sk[2]; sk7 = sk[3];
  }

  const float* lpn = lp + (size_t)n * C;

  if (wid != 0) {
    // ================= producers =================
    const int pidx = (wid < 4) ? (wid - 1) : (wid - 2);  // 0..5
    const int rb0 = pidx * RTW;
    if (lane == 0) rowtmp[rb0 + 128] = 0.f;  // zero slot
    double acc = 0.0;
    int t = pidx;
    float2 c0 = make_float2(0.f, 0.f), c1 = make_float2(0.f, 0.f);
    if (t < Tn) c0 = *(const float2*)(lpn + (size_t)t * NC + 2 * lane);
    if (t + 6 < Tn) c1 = *(const float2*)(lpn + (size_t)(t + 6) * NC + 2 * lane);
    for (; t < Tn; t += 6) {
      float2 v = c0; c0 = c1;
      { int tf = t + 12;
        if (tf < Tn) c1 = *(const float2*)(lpn + (size_t)tf * NC + 2 * lane); }
      float ex = __expf(v.x), ey = __expf(v.y);
      *(float2*)&rowtmp[rb0 + 2 * lane] = make_float2(ex, ey);
      float se = wave_fsum_dpp(ex + ey);  // total on lane 63
      // gather (in-order after the staging write of this wave)
      float g1 = rowtmp[rb0 + i1];
      float g3 = rowtmp[rb0 + i3];
      float g5 = rowtmp[rb0 + i5];
      float g7 = rowtmp[rb0 + i7];
      float gb = rowtmp[rb0 + CTC_BLANK];
      // ring-full wait: slot's previous row (t-64) must be consumed
      while (*(volatile int*)&cons < t - RING) __builtin_amdgcn_s_sleep(8);
      asm volatile("" ::: "memory");
      int sb = (t & (RING - 1)) * GRS;
      *(float4*)&ring[sb + 4 * lane] = make_float4(g1, g3, g5, g7);
      if (lane == 0) ring[sb + 256] = gb;
      asm volatile("" ::: "memory");
      if (lane == 0) *(volatile int*)&prog[pidx] = t;  // in-order after data
      acc += (double)__logf(se);  // only lane 63's acc is meaningful
    }
    if (lane == 63) ws_lse[n * 6 + pidx] = acc;
    return;
  }

  // ================= consumer (wave 0) =================
  const int TnM1 = Tn - 1;
  SPIN_PROG(3)  // rows 0..3 available
  // row 0 -> alpha init; row 1 -> pA
  float4 q0 = *(const float4*)&ring[0 * GRS + 4 * lane];
  float pb0 = ring[0 * GRS + 256];
  float4 qv1 = *(const float4*)&ring[(1 <= TnM1 ? 1 : TnM1) * GRS + 4 * lane];
  float qb1 = ring[(1 <= TnM1 ? 1 : TnM1) * GRS + 256];
  Pv pA, pB;
  pA.pb = (double)qb1; pA.p1 = (double)qv1.x; pA.p3 = (double)qv1.y;
  pA.p5 = (double)qv1.z; pA.p7 = (double)qv1.w;
  double a[8], a8 = 0.0;
  a[0] = (lane == 0) ? (double)pb0 : 0.0;
  a[1] = (lane == 0) ? (double)q0.x : 0.0;
#pragma unroll
  for (int s = 2; s < 8; ++s) a[s] = 0.0;
  // raw reads in flight: qA <- row 2, qB <- row 3
  int r2 = (2 <= TnM1) ? 2 : TnM1, r3 = (3 <= TnM1) ? 3 : TnM1;
  float4 qA = *(const float4*)&ring[r2 * GRS + 4 * lane];
  float qbA = ring[r2 * GRS + 256];
  float4 qB = *(const float4*)&ring[r3 * GRS + 4 * lane];
  float qbB = ring[r3 * GRS + 256];
  asm volatile("" ::: "memory");
  if (lane == 0) *(volatile int*)&cons = 1;  // rows <= 1 consumed

  double hA = 0.0, hB = 0.0;
  long long Esum = 0;
  int t0 = 1;

  for (; t0 + 16 <= Tn; t0 += 16) {
    asm volatile("" ::: "memory");
    if (lane == 0) *(volatile int*)&cons = t0;  // rows <= t0 consumed
    SPIN_PROG(t0 + 18)  // body reads rows up to t0+18
    CSTEP(0,  pA, pB, qA, qbA, hA, hB)
    CSTEP(1,  pB, pA, qB, qbB, hB, hA)
    CSTEP(2,  pA, pB, qA, qbA, hA, hB)
    CSTEP(3,  pB, pA, qB, qbB, hB, hA)
    CSTEP(4,  pA, pB, qA, qbA, hA, hB)
    CSTEP(5,  pB, pA, qB, qbB, hB, hA)
    CSTEP(6,  pA, pB, qA, qbA, hA, hB)
    CSTEP(7,  pB, pA, qB, qbB, hB, hA)
    CSTEP(8,  pA, pB, qA, qbA, hA, hB)
    CSTEP(9,  pB, pA, qB, qbB, hB, hA)
    CSTEP(10, pA, pB, qA, qbA, hA, hB)
    CSTEP(11, pB, pA, qB, qbB, hB, hA)
    CSTEP(12, pA, pB, qA, qbA, hA, hB)
    CSTEP(13, pB, pA, qB, qbB, hB, hA)
    CSTEP(14, pA, pB, qA, qbA, hA, hB)
    CSTEP(15, pB, pA, qB, qbB, hB, hA)
    // renorm every 16: int-compare hi-words, DPP wave max, exact pow2 rescale
    int hi = __double2hiint(a[0]);
    hi = imax2(hi, __double2hiint(a[1]));
    hi = imax2(hi, __double2hiint(a[2]));
    hi = imax2(hi, __double2hiint(a[3]));
    hi = imax2(hi, __double2hiint(a[4]));
    hi = imax2(hi, __double2hiint(a[5]));
    hi = imax2(hi, __double2hiint(a[6]));
    hi = imax2(hi, __double2hiint(a[7]));
    hi = imax2(hi, __double2hiint(a8));
    int mx = wave_imax_dpp(hi);
    int E = ((mx >> 20) & 0x7ff) - 1023;
    double sc = __hiloint2double((1023 - E) << 20, 0);  // exact 2^-E
    Esum += E;
#pragma unroll
    for (int s = 0; s < 8; ++s) a[s] *= sc;
    a8 *= sc;
    hA *= sc;  // pending halo carries the same scale
  }
  // tail (< 16 steps)
  asm volatile("" ::: "memory");
  if (lane == 0) *(volatile int*)&cons = t0;
  SPIN_PROG(Tn)  // capped at Tn-6 -> proves ALL rows produced
  if (t0 + 0  < Tn) CSTEP(0,  pA, pB, qA, qbA, hA, hB)
  if (t0 + 1  < Tn) CSTEP(1,  pB, pA, qB, qbB, hB, hA)
  if (t0 + 2  < Tn) CSTEP(2,  pA, pB, qA, qbA, hA, hB)
  if (t0 + 3  < Tn) CSTEP(3,  pB, pA, qB, qbB, hB, hA)
  if (t0 + 4  < Tn) CSTEP(4,  pA, pB, qA, qbA, hA, hB)
  if (t0 + 5  < Tn) CSTEP(5,  pB, pA, qB, qbB, hB, hA)
  if (t0 + 6  < Tn) CSTEP(6,  pA, pB, qA, qbA, hA, hB)
  if (t0 + 7  < Tn) CSTEP(7,  pB, pA, qB, qbB, hB, hA)
  if (t0 + 8  < Tn) CSTEP(8,  pA, pB, qA, qbA, hA, hB)
  if (t0 + 9  < Tn) CSTEP(9,  pB, pA, qB, qbB, hB, hA)
  if (t0 + 10 < Tn) CSTEP(10, pA, pB, qA, qbA, hA, hB)
  if (t0 + 11 < Tn) CSTEP(11, pB, pA, qB, qbB, hB, hA)
  if (t0 + 12 < Tn) CSTEP(12, pA, pB, qA, qbA, hA, hB)
  if (t0 + 13 < Tn) CSTEP(13, pB, pA, qB, qbB, hB, hA)
  if (t0 + 14 < Tn) CSTEP(14, pA, pB, qA, qbA, hA, hB)

  asm volatile("" ::: "memory");
  if (lane == 0) *(volatile int*)&cons = Tn;  // release producers

  // epilogue
#pragma unroll
  for (int s = 0; s < 8; ++s) adump[lane * 8 + s] = a[s];
  if (lane == 63) adump[512] = a8;
  if (lane == 0) {
    int end = gend;
    int i2 = (end > 0) ? (end - 1) : (2 * L);
    double Ae = adump[end] + adump[i2];
    ws_ll[n] = log(Ae) + (double)Esum * 0.69314718055994530942;
  }
}

__global__ void ctc_final(const double* __restrict__ ws_lse,
                          const double* __restrict__ ws_ll,
                          float* __restrict__ out, int N) {
  __shared__ double sred[128];
  const int i = threadIdx.x;
  double l = 0.0;
  if (i < N) {
    double denom = 0.0;
#pragma unroll
    for (int h = 0; h < 6; ++h) denom += ws_lse[i * 6 + h];
    double ll = ws_ll[i] - denom;
    double ls = -ll;
    if (!isfinite(ls) || fabs(ls) >= 1e29) ls = 0.0;
    l = ls;
  }
  sred[i] = l;
  __syncthreads();
#pragma unroll
  for (int off = 64; off > 0; off >>= 1) {
    if (i < off) sred[i] += sred[i + off];
    __syncthreads();
  }
  if (i == 0) out[0] = (float)sred[0];
}

extern "C" void kernel_launch(void* const* d_in, const int* in_sizes, int n_in,
                              void* d_out, int out_size, void* d_ws, size_t ws_size,
                              hipStream_t stream) {
  (void)n_in; (void)out_size; (void)ws_size;
  const float* lp = (const float*)d_in[0];
  const int* ilen = (const int*)d_in[1];
  const int* tgt = (const int*)d_in[2];
  const int* tlen = (const int*)d_in[3];

  const int N = in_sizes[1];            // 128
  const int L = in_sizes[2] / N;        // 256
  const int C = 128;                    // classes (fixed by problem)
  const int T = in_sizes[0] / (N * C);  // 4000

  double* ws_lse = (double*)d_ws;           // N*6 doubles
  double* ws_ll = ws_lse + (size_t)N * 6;   // N doubles

  ctc_main<<<N, 512, 0, stream>>>(lp, ilen, tgt, tlen, T, N, C, L, ws_lse, ws_ll);
  ctc_final<<<1, 128, 0, stream>>>(ws_lse, ws_ll, (float*)d_out, N);
}